// Round 1
// baseline (857.907 us; speedup 1.0000x reference)
//
#include <hip/hip_runtime.h>

#define NB 1024
#define NT 256
#define IND 10
#define HID 64

// x row layout (523): [sig1(0..10) | sig2f(11..131) | sig3: 1*sig2f(132..252),
//   rel0*sig2f(253..373), rel1*sig2f(374..494), rel2*sig2f[0:17](495..511) |
//   features(512..521) | prev_delta(522)]
__global__ __launch_bounds__(256) void logsig_hedge_kernel(
    const float* __restrict__ features,  // (1024, 256, 10)
    const float* __restrict__ W1,        // (523, 64) row-major
    const float* __restrict__ b1,        // (64)
    const float* __restrict__ W2,        // (64, 64) row-major
    const float* __restrict__ b2,        // (64)
    const float* __restrict__ W3,        // (64, 1)
    const float* __restrict__ b3,        // (1)
    float* __restrict__ out)             // (1024, 256)
{
    const int b = blockIdx.x;
    const int tid = threadIdx.x;
    const int j = tid & 63;   // output column
    const int s = tid >> 6;   // slice 0..3

    __shared__ __align__(16) float sF[NT * IND];   // all features for this b
    __shared__ __align__(16) float sSig[128];      // sig2f (121) + zero pad
    __shared__ float sA[IND], sB[IND], sC[IND * IND];
    __shared__ float sRel[IND];
    __shared__ __align__(16) float sPart[4 * 64];
    __shared__ __align__(16) float sH1[64];

    // ---- init: load this batch's features (coalesced), zero state ----
    for (int idx = tid; idx < NT * IND; idx += 256)
        sF[idx] = features[b * (NT * IND) + idx];
    if (tid < 100) sC[tid] = 0.f;
    else if (tid < 110) sA[tid - 100] = 0.f;
    else if (tid < 120) sB[tid - 110] = 0.f;
    else if (tid >= 121 && tid < 128) sSig[tid] = 0.f;  // pad stays zero

    // ---- per-thread register-resident weight columns ----
    // slice s covers sig2f indices [32s, 32s+32)  (121..127 -> zero weights)
    float vs[32], vb[32], vc[32];
#pragma unroll
    for (int mm = 0; mm < 32; ++mm) {
        int mp = 32 * s + mm;
        if (mp < 121) {
            vs[mm] = W1[(11 + mp) * 64 + j] + W1[(132 + mp) * 64 + j];
            vb[mm] = W1[(253 + mp) * 64 + j];
            vc[mm] = W1[(374 + mp) * 64 + j];
        } else { vs[mm] = 0.f; vb[mm] = 0.f; vc[mm] = 0.f; }
    }
    // slice-specific extras share one array:
    //   s==1: ex[0..10] = W1 rows 0..10 (sig1 weights)
    //   s==2: ex[0..9]  = W1 rows 512..521 (feature weights), ex[10] = b1[j]
    //   s==3: ex[0..16] = W1 rows 495..511 (rel2*sig2f[0:17] weights)
    float ex[17];
#pragma unroll
    for (int t = 0; t < 17; ++t) ex[t] = 0.f;
    if (s == 1) {
#pragma unroll
        for (int t = 0; t < 11; ++t) ex[t] = W1[t * 64 + j];
    } else if (s == 2) {
#pragma unroll
        for (int t = 0; t < 10; ++t) ex[t] = W1[(512 + t) * 64 + j];
        ex[10] = b1[j];
    } else if (s == 3) {
#pragma unroll
        for (int t = 0; t < 17; ++t) ex[t] = W1[(495 + t) * 64 + j];
    }
    // W2 rows [16s, 16s+16) column j
    float w2p[16];
#pragma unroll
    for (int ii = 0; ii < 16; ++ii) w2p[ii] = W2[(16 * s + ii) * 64 + j];

    float w1l = 0.f, b2j = 0.f, w3j = 0.f, b3v = 0.f;
    if (s == 0) { w1l = W1[522 * 64 + j]; b2j = b2[j]; w3j = W3[j]; b3v = b3[0]; }
    float delta = 0.f;  // per-batch scan state (wave 0, uniform across lanes)

    __syncthreads();

    for (int m = 0; m < NT; ++m) {
        if (m > 0) {
            // ---- P1: add step r=m-1 into cumulative state ----
            if (tid < 100) {
                int i = tid / 10, c = tid % 10;
                float rp = sF[(m - 1) * 10 + i] - sF[i];            // rel[m-1,i]
                float ic = sF[m * 10 + c] - sF[(m - 1) * 10 + c];   // inc[m-1,c]
                sC[tid] += rp * ic;
            } else if (tid < 110) {
                int i = tid - 100;
                sA[i] += (float)(m - 1) * (sF[m * 10 + i] - sF[(m - 1) * 10 + i]);
            } else if (tid < 120) {
                int i = tid - 110;
                sB[i] += sF[(m - 1) * 10 + i] - sF[i];
            }
            __syncthreads();
            // ---- P2: build sig2f (121) and rel_cur (10) ----
            float inv_k = 1.0f / (float)m;
            if (tid == 0) {
                sSig[0] = 0.5f * (float)(m - 1) * inv_k;            // tt
            } else if (tid < 11) {
                sSig[tid] = inv_k * sA[tid - 1];
            } else if (tid < 121) {
                int i = tid / 11 - 1, c = tid % 11;
                sSig[tid] = (c == 0) ? inv_k * sB[i] : sC[i * 10 + (c - 1)];
            } else if (tid < 131) {
                int f = tid - 121;
                sRel[f] = sF[m * 10 + f] - sF[f];                   // rel[m,f]
            }
            __syncthreads();
        }
        // ---- P3: pre-activation partials (x @ W1 column j, slice s) ----
        float part = 0.f;
        if (m > 0) {
            float pa = 0.f, pb = 0.f, pc = 0.f;
#pragma unroll
            for (int q = 0; q < 8; ++q) {
                float4 sv = *(const float4*)&sSig[32 * s + 4 * q];
                pa = fmaf(sv.x, vs[4 * q + 0], pa);
                pb = fmaf(sv.x, vb[4 * q + 0], pb);
                pc = fmaf(sv.x, vc[4 * q + 0], pc);
                pa = fmaf(sv.y, vs[4 * q + 1], pa);
                pb = fmaf(sv.y, vb[4 * q + 1], pb);
                pc = fmaf(sv.y, vc[4 * q + 1], pc);
                pa = fmaf(sv.z, vs[4 * q + 2], pa);
                pb = fmaf(sv.z, vb[4 * q + 2], pb);
                pc = fmaf(sv.z, vc[4 * q + 2], pc);
                pa = fmaf(sv.w, vs[4 * q + 3], pa);
                pb = fmaf(sv.w, vb[4 * q + 3], pb);
                pc = fmaf(sv.w, vc[4 * q + 3], pc);
            }
            part = pa + sRel[0] * pb + sRel[1] * pc;
            if (s == 3) {   // rel2 * sig2f[0:17] segment
                float pd = 0.f;
#pragma unroll
                for (int t = 0; t < 17; ++t) pd = fmaf(sSig[t], ex[t], pd);
                part = fmaf(sRel[2], pd, part);
            }
            if (s == 1) {   // sig1: 1*W1[0,j] + rel·W1[1..10,j]
                part += ex[0];
#pragma unroll
                for (int i = 0; i < 10; ++i) part = fmaf(sRel[i], ex[1 + i], part);
            }
        }
        if (s == 2) {       // features + bias (valid for all m incl. m==0)
            float pf = ex[10];
#pragma unroll
            for (int f = 0; f < 10; ++f) pf = fmaf(sF[m * 10 + f], ex[f], pf);
            part += pf;
        }
        sPart[s * 64 + j] = part;
        __syncthreads();
        // ---- P4: wave0 computes h1 ----
        if (s == 0) {
            float x = sPart[j] + sPart[64 + j] + sPart[128 + j] + sPart[192 + j];
            float h1 = fmaxf(fmaf(delta, w1l, x), 0.f);
            sH1[j] = h1;
        }
        __syncthreads();
        // ---- P5: h2 partials (W2 rows [16s,16s+16)) ----
        {
            float hp = 0.f;
#pragma unroll
            for (int q = 0; q < 4; ++q) {
                float4 hv = *(const float4*)&sH1[16 * s + 4 * q];
                hp = fmaf(hv.x, w2p[4 * q + 0], hp);
                hp = fmaf(hv.y, w2p[4 * q + 1], hp);
                hp = fmaf(hv.z, w2p[4 * q + 2], hp);
                hp = fmaf(hv.w, w2p[4 * q + 3], hp);
            }
            sPart[s * 64 + j] = hp;
        }
        __syncthreads();
        // ---- P6: wave0 computes h2, delta, writes out ----
        if (s == 0) {
            float x2 = sPart[j] + sPart[64 + j] + sPart[128 + j] + sPart[192 + j] + b2j;
            float h2 = fmaxf(x2, 0.f);
            float dv = h2 * w3j;
#pragma unroll
            for (int off = 32; off > 0; off >>= 1) dv += __shfl_xor(dv, off, 64);
            delta = dv + b3v;
            if (j == 0) out[b * NT + m] = delta;
        }
        __syncthreads();
    }
}

extern "C" void kernel_launch(void* const* d_in, const int* in_sizes, int n_in,
                              void* d_out, int out_size, void* d_ws, size_t ws_size,
                              hipStream_t stream) {
    const float* features = (const float*)d_in[0];
    const float* W1 = (const float*)d_in[1];
    const float* b1 = (const float*)d_in[2];
    const float* W2 = (const float*)d_in[3];
    const float* b2 = (const float*)d_in[4];
    const float* W3 = (const float*)d_in[5];
    const float* b3 = (const float*)d_in[6];
    float* out = (float*)d_out;
    logsig_hedge_kernel<<<NB, NT, 0, stream>>>(features, W1, b1, W2, b2, W3, b3, out);
}

// Round 2
// 672.511 us; speedup vs baseline: 1.2757x; 1.2757x over previous
//
#include <hip/hip_runtime.h>

#define NB 1024
#define NT 256
#define IND 10
#define HID 64
#define WPJ 404   // packed weight floats per output column j

// ---------------------------------------------------------------------------
// Weight repack: Wr[j*WPJ + k] layout per j:
//   0..119   : Ws  (W1[11+q]+W1[132+q]) in payload order [A(10),B(10),C(100)]
//   120..239 : Wb  (W1[253+q]) same order            (gated by rel0)
//   240..359 : Wc  (W1[374+q]) same order            (gated by rel1)
//   360..369 : wdA (W1[495+1+c])                     (gated by rel2)
//   370      : wdB0 (W1[495+11])
//   371..375 : wdC (W1[495+12+c])
//   376..385 : wrel (W1[1+c])        (sig1)
//   386..395 : wf   (W1[512+c])      (features)
//   396..399 : ws_tt, wb_tt, wc_tt, wd_tt  (sig2f[0] coefs)
//   400      : w_one (W1[0])
//   401      : b1[j]
//   402..403 : pad (0)
// payload order: q=1+c (A), q=11*(i+1) (B), q=11*(i+1)+1+c (C)
// ---------------------------------------------------------------------------
__device__ __forceinline__ int qmap(int kk) {
    if (kk < 10) return 1 + kk;
    if (kk < 20) return 11 * (kk - 10 + 1);
    int i = (kk - 20) / 10, c = (kk - 20) % 10;
    return 11 * (i + 1) + 1 + c;
}

__global__ void pack_kernel(const float* __restrict__ W1, const float* __restrict__ b1,
                            float* __restrict__ Wr) {
    int idx = blockIdx.x * 256 + threadIdx.x;
    if (idx >= 64 * WPJ) return;
    int j = idx / WPJ, k = idx % WPJ;
    float v = 0.f;
    if (k < 120)       { int q = qmap(k);       v = W1[(11+q)*64+j] + W1[(132+q)*64+j]; }
    else if (k < 240)  { int q = qmap(k - 120); v = W1[(253+q)*64+j]; }
    else if (k < 360)  { int q = qmap(k - 240); v = W1[(374+q)*64+j]; }
    else if (k < 370)  { v = W1[(495 + 1 + (k-360))*64 + j]; }
    else if (k == 370) { v = W1[(495 + 11)*64 + j]; }
    else if (k < 376)  { v = W1[(495 + 12 + (k-371))*64 + j]; }
    else if (k < 386)  { v = W1[(1 + (k-376))*64 + j]; }
    else if (k < 396)  { v = W1[(512 + (k-386))*64 + j]; }
    else if (k == 396) { v = W1[11*64+j] + W1[132*64+j]; }
    else if (k == 397) { v = W1[253*64+j]; }
    else if (k == 398) { v = W1[374*64+j]; }
    else if (k == 399) { v = W1[495*64+j]; }
    else if (k == 400) { v = W1[0*64+j]; }
    else if (k == 401) { v = b1[j]; }
    Wr[idx] = v;
}

// ---------------------------------------------------------------------------
// Kernel A: parallel-over-t pre-activation.  thread t in block b computes
// pre1[b][t][j] for all 64 j.  Exclusive prefix sums of the 120-float step
// payload [t*inc(10), rel(10), rel_i*inc_c(100)] via wave shuffle scan.
// ---------------------------------------------------------------------------
__global__ __launch_bounds__(256) void presig_kernel(
    const float* __restrict__ features, const float* __restrict__ Wr,
    float* __restrict__ pre1) {
    const int b = blockIdx.x;
    const int t = threadIdx.x;
    const int lane = t & 63;
    const int w = t >> 6;

    __shared__ __align__(16) float sF[NT * IND];
    __shared__ float sWS[3][120];

    {
        const float4* src = (const float4*)(features + b * (NT * IND));
        float4* dst = (float4*)sF;
        for (int idx = t; idx < NT * IND / 4; idx += 256) dst[idx] = src[idx];
    }
    __syncthreads();

    float F[10], rel[10], inc[10], P[120];
#pragma unroll
    for (int f = 0; f < 10; ++f) F[f] = sF[t * 10 + f];
#pragma unroll
    for (int f = 0; f < 10; ++f) rel[f] = F[f] - sF[f];
#pragma unroll
    for (int f = 0; f < 10; ++f)
        inc[f] = (t < 255) ? (sF[(t + 1) * 10 + f] - F[f]) : 0.f;

    // step payload
    float tf = (float)t;
#pragma unroll
    for (int c = 0; c < 10; ++c) P[c] = tf * inc[c];
#pragma unroll
    for (int i = 0; i < 10; ++i) P[10 + i] = rel[i];
#pragma unroll
    for (int i = 0; i < 10; ++i)
#pragma unroll
        for (int c = 0; c < 10; ++c) P[20 + i * 10 + c] = rel[i] * inc[c];

    // wave-level inclusive scan
#pragma unroll
    for (int d = 1; d < 64; d <<= 1) {
#pragma unroll
        for (int k = 0; k < 120; ++k) {
            float v = __shfl_up(P[k], d, 64);
            if (lane >= d) P[k] += v;
        }
    }
    // cross-wave fixup
    if (lane == 63 && w < 3) {
#pragma unroll
        for (int k = 0; k < 120; ++k) sWS[w][k] = P[k];
    }
    __syncthreads();
    for (int w2 = 0; w2 < w; ++w2) {
#pragma unroll
        for (int k = 0; k < 120; ++k) P[k] += sWS[w2][k];
    }
    // inclusive -> exclusive: subtract own step
#pragma unroll
    for (int c = 0; c < 10; ++c) P[c] = fmaf(-tf, inc[c], P[c]);
#pragma unroll
    for (int i = 0; i < 10; ++i) P[10 + i] -= rel[i];
#pragma unroll
    for (int i = 0; i < 10; ++i)
#pragma unroll
        for (int c = 0; c < 10; ++c) P[20 + i * 10 + c] = fmaf(-rel[i], inc[c], P[20 + i * 10 + c]);

    // fold inv_k into A,B sections
    float inv_k = (t > 0) ? 1.f / tf : 0.f;
    float tt = 0.5f * (tf - 1.f) * inv_k;
#pragma unroll
    for (int k = 0; k < 20; ++k) P[k] *= inv_k;

    float w_one_gate = (t > 0) ? 1.f : 0.f;
    float* outp = pre1 + b * (NT * HID) + t * HID;

    const float* wj = Wr;
    for (int j = 0; j < 64; ++j, wj += WPJ) {
        float a0 = 0.f, a1 = 0.f, b0 = 0.f, b1_ = 0.f, c0 = 0.f, c1 = 0.f;
#pragma unroll
        for (int k = 0; k < 120; k += 4) {
            float4 ws4 = *(const float4*)(wj + k);
            float4 wb4 = *(const float4*)(wj + 120 + k);
            float4 wc4 = *(const float4*)(wj + 240 + k);
            a0 = fmaf(P[k + 0], ws4.x, a0); a1 = fmaf(P[k + 1], ws4.y, a1);
            a0 = fmaf(P[k + 2], ws4.z, a0); a1 = fmaf(P[k + 3], ws4.w, a1);
            b0 = fmaf(P[k + 0], wb4.x, b0); b1_ = fmaf(P[k + 1], wb4.y, b1_);
            b0 = fmaf(P[k + 2], wb4.z, b0); b1_ = fmaf(P[k + 3], wb4.w, b1_);
            c0 = fmaf(P[k + 0], wc4.x, c0); c1 = fmaf(P[k + 1], wc4.y, c1);
            c0 = fmaf(P[k + 2], wc4.z, c0); c1 = fmaf(P[k + 3], wc4.w, c1);
        }
        float dd = tt * wj[399];
#pragma unroll
        for (int c = 0; c < 10; ++c) dd = fmaf(P[c], wj[360 + c], dd);
        dd = fmaf(P[10], wj[370], dd);
#pragma unroll
        for (int c = 0; c < 5; ++c) dd = fmaf(P[20 + c], wj[371 + c], dd);

        float ds = a0 + a1 + tt * wj[396];
        float db = b0 + b1_ + tt * wj[397];
        float dc = c0 + c1 + tt * wj[398];
        float pre = ds + rel[0] * db + rel[1] * dc + rel[2] * dd;
        pre = fmaf(w_one_gate, wj[400], pre);
#pragma unroll
        for (int c = 0; c < 10; ++c) pre = fmaf(rel[c], wj[376 + c], pre);
#pragma unroll
        for (int c = 0; c < 10; ++c) pre = fmaf(F[c], wj[386 + c], pre);
        pre += wj[401];
        outp[j] = pre;
    }
}

// ---------------------------------------------------------------------------
// Kernel B: per-batch sequential scan, one wave per batch.  No multi-wave
// barriers; h1 broadcast via LDS within the wave; delta via butterfly shuffle.
// ---------------------------------------------------------------------------
__global__ __launch_bounds__(64) void scan_kernel(
    const float* __restrict__ pre1, const float* __restrict__ W1,
    const float* __restrict__ W2, const float* __restrict__ b2,
    const float* __restrict__ W3, const float* __restrict__ b3,
    float* __restrict__ out) {
    const int b = blockIdx.x;
    const int j = threadIdx.x;

    __shared__ __align__(16) float sH[64];

    float w2c[64];
#pragma unroll
    for (int i = 0; i < 64; ++i) w2c[i] = W2[i * 64 + j];
    float w1l = W1[522 * 64 + j];
    float b2j = b2[j], w3j = W3[j], b3v = b3[0];

    const float* pb_ = pre1 + b * (NT * HID);
    float delta = 0.f;
    float p0 = pb_[j];
    float p1 = pb_[64 + j];

    for (int m = 0; m < NT; ++m) {
        float pn = (m + 2 < NT) ? pb_[(m + 2) * 64 + j] : 0.f;
        float h1 = fmaxf(fmaf(delta, w1l, p0), 0.f);
        sH[j] = h1;
        __syncthreads();
        float a0 = 0.f, a1 = 0.f, a2 = 0.f, a3 = 0.f;
#pragma unroll
        for (int i = 0; i < 64; i += 4) {
            float4 hv = *(const float4*)&sH[i];
            a0 = fmaf(hv.x, w2c[i + 0], a0);
            a1 = fmaf(hv.y, w2c[i + 1], a1);
            a2 = fmaf(hv.z, w2c[i + 2], a2);
            a3 = fmaf(hv.w, w2c[i + 3], a3);
        }
        __syncthreads();
        float h2 = fmaxf(a0 + a1 + a2 + a3 + b2j, 0.f);
        float dv = h2 * w3j;
#pragma unroll
        for (int off = 32; off > 0; off >>= 1) dv += __shfl_xor(dv, off, 64);
        delta = dv + b3v;
        if (j == 0) out[b * NT + m] = delta;
        p0 = p1;
        p1 = pn;
    }
}

// ---------------------------------------------------------------------------
// Fallback (round-1 fused kernel) if workspace is too small for pre1.
// ---------------------------------------------------------------------------
__global__ __launch_bounds__(256) void logsig_hedge_fallback(
    const float* __restrict__ features, const float* __restrict__ W1,
    const float* __restrict__ b1, const float* __restrict__ W2,
    const float* __restrict__ b2, const float* __restrict__ W3,
    const float* __restrict__ b3, float* __restrict__ out) {
    const int b = blockIdx.x;
    const int tid = threadIdx.x;
    const int j = tid & 63;
    const int s = tid >> 6;

    __shared__ __align__(16) float sF[NT * IND];
    __shared__ __align__(16) float sSig[128];
    __shared__ float sA[IND], sB[IND], sC[IND * IND];
    __shared__ float sRel[IND];
    __shared__ __align__(16) float sPart[4 * 64];
    __shared__ __align__(16) float sH1[64];

    for (int idx = tid; idx < NT * IND; idx += 256)
        sF[idx] = features[b * (NT * IND) + idx];
    if (tid < 100) sC[tid] = 0.f;
    else if (tid < 110) sA[tid - 100] = 0.f;
    else if (tid < 120) sB[tid - 110] = 0.f;
    else if (tid >= 121 && tid < 128) sSig[tid] = 0.f;

    float vs[32], vb[32], vc[32];
#pragma unroll
    for (int mm = 0; mm < 32; ++mm) {
        int mp = 32 * s + mm;
        if (mp < 121) {
            vs[mm] = W1[(11 + mp) * 64 + j] + W1[(132 + mp) * 64 + j];
            vb[mm] = W1[(253 + mp) * 64 + j];
            vc[mm] = W1[(374 + mp) * 64 + j];
        } else { vs[mm] = 0.f; vb[mm] = 0.f; vc[mm] = 0.f; }
    }
    float ex[17];
#pragma unroll
    for (int q = 0; q < 17; ++q) ex[q] = 0.f;
    if (s == 1) {
#pragma unroll
        for (int q = 0; q < 11; ++q) ex[q] = W1[q * 64 + j];
    } else if (s == 2) {
#pragma unroll
        for (int q = 0; q < 10; ++q) ex[q] = W1[(512 + q) * 64 + j];
        ex[10] = b1[j];
    } else if (s == 3) {
#pragma unroll
        for (int q = 0; q < 17; ++q) ex[q] = W1[(495 + q) * 64 + j];
    }
    float w2p[16];
#pragma unroll
    for (int ii = 0; ii < 16; ++ii) w2p[ii] = W2[(16 * s + ii) * 64 + j];

    float w1l = 0.f, b2j = 0.f, w3j = 0.f, b3v = 0.f;
    if (s == 0) { w1l = W1[522 * 64 + j]; b2j = b2[j]; w3j = W3[j]; b3v = b3[0]; }
    float delta = 0.f;

    __syncthreads();

    for (int m = 0; m < NT; ++m) {
        if (m > 0) {
            if (tid < 100) {
                int i = tid / 10, c = tid % 10;
                float rp = sF[(m - 1) * 10 + i] - sF[i];
                float ic = sF[m * 10 + c] - sF[(m - 1) * 10 + c];
                sC[tid] += rp * ic;
            } else if (tid < 110) {
                int i = tid - 100;
                sA[i] += (float)(m - 1) * (sF[m * 10 + i] - sF[(m - 1) * 10 + i]);
            } else if (tid < 120) {
                int i = tid - 110;
                sB[i] += sF[(m - 1) * 10 + i] - sF[i];
            }
            __syncthreads();
            float inv_k = 1.0f / (float)m;
            if (tid == 0) sSig[0] = 0.5f * (float)(m - 1) * inv_k;
            else if (tid < 11) sSig[tid] = inv_k * sA[tid - 1];
            else if (tid < 121) {
                int i = tid / 11 - 1, c = tid % 11;
                sSig[tid] = (c == 0) ? inv_k * sB[i] : sC[i * 10 + (c - 1)];
            } else if (tid < 131) {
                int f = tid - 121;
                sRel[f] = sF[m * 10 + f] - sF[f];
            }
            __syncthreads();
        }
        float part = 0.f;
        if (m > 0) {
            float pa = 0.f, pb = 0.f, pc = 0.f;
#pragma unroll
            for (int q = 0; q < 8; ++q) {
                float4 sv = *(const float4*)&sSig[32 * s + 4 * q];
                pa = fmaf(sv.x, vs[4 * q + 0], pa);
                pb = fmaf(sv.x, vb[4 * q + 0], pb);
                pc = fmaf(sv.x, vc[4 * q + 0], pc);
                pa = fmaf(sv.y, vs[4 * q + 1], pa);
                pb = fmaf(sv.y, vb[4 * q + 1], pb);
                pc = fmaf(sv.y, vc[4 * q + 1], pc);
                pa = fmaf(sv.z, vs[4 * q + 2], pa);
                pb = fmaf(sv.z, vb[4 * q + 2], pb);
                pc = fmaf(sv.z, vc[4 * q + 2], pc);
                pa = fmaf(sv.w, vs[4 * q + 3], pa);
                pb = fmaf(sv.w, vb[4 * q + 3], pb);
                pc = fmaf(sv.w, vc[4 * q + 3], pc);
            }
            part = pa + sRel[0] * pb + sRel[1] * pc;
            if (s == 3) {
                float pd = 0.f;
#pragma unroll
                for (int q = 0; q < 17; ++q) pd = fmaf(sSig[q], ex[q], pd);
                part = fmaf(sRel[2], pd, part);
            }
            if (s == 1) {
                part += ex[0];
#pragma unroll
                for (int i = 0; i < 10; ++i) part = fmaf(sRel[i], ex[1 + i], part);
            }
        }
        if (s == 2) {
            float pf = ex[10];
#pragma unroll
            for (int f = 0; f < 10; ++f) pf = fmaf(sF[m * 10 + f], ex[f], pf);
            part += pf;
        }
        sPart[s * 64 + j] = part;
        __syncthreads();
        if (s == 0) {
            float x = sPart[j] + sPart[64 + j] + sPart[128 + j] + sPart[192 + j];
            sH1[j] = fmaxf(fmaf(delta, w1l, x), 0.f);
        }
        __syncthreads();
        {
            float hp = 0.f;
#pragma unroll
            for (int q = 0; q < 4; ++q) {
                float4 hv = *(const float4*)&sH1[16 * s + 4 * q];
                hp = fmaf(hv.x, w2p[4 * q + 0], hp);
                hp = fmaf(hv.y, w2p[4 * q + 1], hp);
                hp = fmaf(hv.z, w2p[4 * q + 2], hp);
                hp = fmaf(hv.w, w2p[4 * q + 3], hp);
            }
            sPart[s * 64 + j] = hp;
        }
        __syncthreads();
        if (s == 0) {
            float x2 = sPart[j] + sPart[64 + j] + sPart[128 + j] + sPart[192 + j] + b2j;
            float h2 = fmaxf(x2, 0.f);
            float dv = h2 * w3j;
#pragma unroll
            for (int off = 32; off > 0; off >>= 1) dv += __shfl_xor(dv, off, 64);
            delta = dv + b3v;
            if (j == 0) out[b * NT + m] = delta;
        }
        __syncthreads();
    }
}

extern "C" void kernel_launch(void* const* d_in, const int* in_sizes, int n_in,
                              void* d_out, int out_size, void* d_ws, size_t ws_size,
                              hipStream_t stream) {
    const float* features = (const float*)d_in[0];
    const float* W1 = (const float*)d_in[1];
    const float* b1 = (const float*)d_in[2];
    const float* W2 = (const float*)d_in[3];
    const float* b2 = (const float*)d_in[4];
    const float* W3 = (const float*)d_in[5];
    const float* b3 = (const float*)d_in[6];
    float* out = (float*)d_out;

    const size_t wr_bytes = (size_t)64 * WPJ * sizeof(float);     // 103,424
    const size_t wr_pad   = 103936;                               // 256B-aligned
    const size_t pre_bytes = (size_t)NB * NT * HID * sizeof(float); // 64 MiB
    if (ws_size >= wr_pad + pre_bytes) {
        float* Wr = (float*)d_ws;
        float* pre1 = (float*)((char*)d_ws + wr_pad);
        pack_kernel<<<(64 * WPJ + 255) / 256, 256, 0, stream>>>(W1, b1, Wr);
        presig_kernel<<<NB, NT, 0, stream>>>(features, Wr, pre1);
        scan_kernel<<<NB, 64, 0, stream>>>(pre1, W1, W2, b2, W3, b3, out);
    } else {
        logsig_hedge_fallback<<<NB, NT, 0, stream>>>(features, W1, b1, W2, b2, W3, b3, out);
    }
}

// Round 3
// 665.071 us; speedup vs baseline: 1.2899x; 1.0112x over previous
//
#include <hip/hip_runtime.h>

#define NB 1024
#define NT 256
#define IND 10
#define HID 64
#define WPJ 404   // packed weight floats per output column j

// ---------------------------------------------------------------------------
// Weight repack: Wr[j*WPJ + k] layout per j:
//   0..119   : Ws  (W1[11+q]+W1[132+q]) in payload order [A(10),B(10),C(100)]
//   120..239 : Wb  (W1[253+q]) same order            (gated by rel0)
//   240..359 : Wc  (W1[374+q]) same order            (gated by rel1)
//   360..369 : wdA (W1[495+1+c])                     (gated by rel2)
//   370      : wdB0 (W1[495+11])
//   371..375 : wdC (W1[495+12+c])
//   376..385 : wrel (W1[1+c])        (sig1)
//   386..395 : wf   (W1[512+c])      (features)
//   396..399 : ws_tt, wb_tt, wc_tt, wd_tt  (sig2f[0] coefs)
//   400      : w_one (W1[0])
//   401      : b1[j]
//   402..403 : pad (0)
// payload order: q=1+c (A), q=11*(i+1) (B), q=11*(i+1)+1+c (C)
// ---------------------------------------------------------------------------
__device__ __forceinline__ int qmap(int kk) {
    if (kk < 10) return 1 + kk;
    if (kk < 20) return 11 * (kk - 10 + 1);
    int i = (kk - 20) / 10, c = (kk - 20) % 10;
    return 11 * (i + 1) + 1 + c;
}

__global__ void pack_kernel(const float* __restrict__ W1, const float* __restrict__ b1,
                            float* __restrict__ Wr) {
    int idx = blockIdx.x * 256 + threadIdx.x;
    if (idx >= 64 * WPJ) return;
    int j = idx / WPJ, k = idx % WPJ;
    float v = 0.f;
    if (k < 120)       { int q = qmap(k);       v = W1[(11+q)*64+j] + W1[(132+q)*64+j]; }
    else if (k < 240)  { int q = qmap(k - 120); v = W1[(253+q)*64+j]; }
    else if (k < 360)  { int q = qmap(k - 240); v = W1[(374+q)*64+j]; }
    else if (k < 370)  { v = W1[(495 + 1 + (k-360))*64 + j]; }
    else if (k == 370) { v = W1[(495 + 11)*64 + j]; }
    else if (k < 376)  { v = W1[(495 + 12 + (k-371))*64 + j]; }
    else if (k < 386)  { v = W1[(1 + (k-376))*64 + j]; }
    else if (k < 396)  { v = W1[(512 + (k-386))*64 + j]; }
    else if (k == 396) { v = W1[11*64+j] + W1[132*64+j]; }
    else if (k == 397) { v = W1[253*64+j]; }
    else if (k == 398) { v = W1[374*64+j]; }
    else if (k == 399) { v = W1[495*64+j]; }
    else if (k == 400) { v = W1[0*64+j]; }
    else if (k == 401) { v = b1[j]; }
    Wr[idx] = v;
}

// ---------------------------------------------------------------------------
// Kernel A: parallel-over-t pre-activation.  thread t in block b computes
// pre1[b][t][j] for all 64 j.  Exclusive prefix sums of the 120-float step
// payload [t*inc(10), rel(10), rel_i*inc_c(100)] via wave shuffle scan.
// __launch_bounds__(256, 1): the live set is ~170 floats (P[120]+F+rel+inc);
// the default VGPR budget (96) spilled ~900 MB of scratch to HBM in round 2.
// ---------------------------------------------------------------------------
__global__ __launch_bounds__(256, 1) void presig_kernel(
    const float* __restrict__ features, const float* __restrict__ Wr,
    float* __restrict__ pre1) {
    const int b = blockIdx.x;
    const int t = threadIdx.x;
    const int lane = t & 63;
    const int w = t >> 6;

    __shared__ __align__(16) float sF[NT * IND];
    __shared__ float sWS[3][120];

    {
        const float4* src = (const float4*)(features + b * (NT * IND));
        float4* dst = (float4*)sF;
        for (int idx = t; idx < NT * IND / 4; idx += 256) dst[idx] = src[idx];
    }
    __syncthreads();

    float F[10], rel[10], inc[10], P[120];
#pragma unroll
    for (int f = 0; f < 10; ++f) F[f] = sF[t * 10 + f];
#pragma unroll
    for (int f = 0; f < 10; ++f) rel[f] = F[f] - sF[f];
#pragma unroll
    for (int f = 0; f < 10; ++f)
        inc[f] = (t < 255) ? (sF[(t + 1) * 10 + f] - F[f]) : 0.f;

    // step payload
    float tf = (float)t;
#pragma unroll
    for (int c = 0; c < 10; ++c) P[c] = tf * inc[c];
#pragma unroll
    for (int i = 0; i < 10; ++i) P[10 + i] = rel[i];
#pragma unroll
    for (int i = 0; i < 10; ++i)
#pragma unroll
        for (int c = 0; c < 10; ++c) P[20 + i * 10 + c] = rel[i] * inc[c];

    // wave-level inclusive scan
#pragma unroll
    for (int d = 1; d < 64; d <<= 1) {
#pragma unroll
        for (int k = 0; k < 120; ++k) {
            float v = __shfl_up(P[k], d, 64);
            if (lane >= d) P[k] += v;
        }
    }
    // cross-wave fixup
    if (lane == 63 && w < 3) {
#pragma unroll
        for (int k = 0; k < 120; ++k) sWS[w][k] = P[k];
    }
    __syncthreads();
    for (int w2 = 0; w2 < w; ++w2) {
#pragma unroll
        for (int k = 0; k < 120; ++k) P[k] += sWS[w2][k];
    }
    // inclusive -> exclusive: subtract own step
#pragma unroll
    for (int c = 0; c < 10; ++c) P[c] = fmaf(-tf, inc[c], P[c]);
#pragma unroll
    for (int i = 0; i < 10; ++i) P[10 + i] -= rel[i];
#pragma unroll
    for (int i = 0; i < 10; ++i)
#pragma unroll
        for (int c = 0; c < 10; ++c) P[20 + i * 10 + c] = fmaf(-rel[i], inc[c], P[20 + i * 10 + c]);

    // fold inv_k into A,B sections
    float inv_k = (t > 0) ? 1.f / tf : 0.f;
    float tt = 0.5f * (tf - 1.f) * inv_k;
#pragma unroll
    for (int k = 0; k < 20; ++k) P[k] *= inv_k;

    float w_one_gate = (t > 0) ? 1.f : 0.f;
    float* outp = pre1 + b * (NT * HID) + t * HID;

    const float* wj = Wr;
    for (int j = 0; j < 64; ++j, wj += WPJ) {
        float a0 = 0.f, a1 = 0.f, b0 = 0.f, b1_ = 0.f, c0 = 0.f, c1 = 0.f;
#pragma unroll
        for (int k = 0; k < 120; k += 4) {
            float4 ws4 = *(const float4*)(wj + k);
            float4 wb4 = *(const float4*)(wj + 120 + k);
            float4 wc4 = *(const float4*)(wj + 240 + k);
            a0 = fmaf(P[k + 0], ws4.x, a0); a1 = fmaf(P[k + 1], ws4.y, a1);
            a0 = fmaf(P[k + 2], ws4.z, a0); a1 = fmaf(P[k + 3], ws4.w, a1);
            b0 = fmaf(P[k + 0], wb4.x, b0); b1_ = fmaf(P[k + 1], wb4.y, b1_);
            b0 = fmaf(P[k + 2], wb4.z, b0); b1_ = fmaf(P[k + 3], wb4.w, b1_);
            c0 = fmaf(P[k + 0], wc4.x, c0); c1 = fmaf(P[k + 1], wc4.y, c1);
            c0 = fmaf(P[k + 2], wc4.z, c0); c1 = fmaf(P[k + 3], wc4.w, c1);
        }
        float dd = tt * wj[399];
#pragma unroll
        for (int c = 0; c < 10; ++c) dd = fmaf(P[c], wj[360 + c], dd);
        dd = fmaf(P[10], wj[370], dd);
#pragma unroll
        for (int c = 0; c < 5; ++c) dd = fmaf(P[20 + c], wj[371 + c], dd);

        float ds = a0 + a1 + tt * wj[396];
        float db = b0 + b1_ + tt * wj[397];
        float dc = c0 + c1 + tt * wj[398];
        float pre = ds + rel[0] * db + rel[1] * dc + rel[2] * dd;
        pre = fmaf(w_one_gate, wj[400], pre);
#pragma unroll
        for (int c = 0; c < 10; ++c) pre = fmaf(rel[c], wj[376 + c], pre);
#pragma unroll
        for (int c = 0; c < 10; ++c) pre = fmaf(F[c], wj[386 + c], pre);
        pre += wj[401];
        outp[j] = pre;
    }
}

// ---------------------------------------------------------------------------
// Kernel B: per-batch sequential scan, one wave per batch.  No LDS, no
// barriers: h1 is broadcast lane-by-lane via v_readlane (SGPR operand into
// the FMA), delta via butterfly shuffle.  1 wave/SIMD -> pure latency chain,
// so every removed LDS round-trip is wall-clock time.
// ---------------------------------------------------------------------------
__device__ __forceinline__ float rdlane(float v, int i) {
    return __uint_as_float(__builtin_amdgcn_readlane(__float_as_uint(v), i));
}

__global__ __launch_bounds__(64, 1) void scan_kernel(
    const float* __restrict__ pre1, const float* __restrict__ W1,
    const float* __restrict__ W2, const float* __restrict__ b2,
    const float* __restrict__ W3, const float* __restrict__ b3,
    float* __restrict__ out) {
    const int b = blockIdx.x;
    const int j = threadIdx.x;

    float w2c[64];
#pragma unroll
    for (int i = 0; i < 64; ++i) w2c[i] = W2[i * 64 + j];
    float w1l = W1[522 * 64 + j];
    float b2j = b2[j], w3j = W3[j], b3v = b3[0];

    const float* pb_ = pre1 + b * (NT * HID);
    float delta = 0.f;
    float p0 = pb_[j];
    float p1 = pb_[64 + j];

    for (int m = 0; m < NT; ++m) {
        float pn = (m + 2 < NT) ? pb_[(m + 2) * 64 + j] : 0.f;
        float h1 = fmaxf(fmaf(delta, w1l, p0), 0.f);
        // 64x64 GEMV: broadcast h1 from every lane via readlane (no LDS/barrier)
        float a0 = 0.f, a1 = 0.f, a2 = 0.f, a3 = 0.f;
#pragma unroll
        for (int i = 0; i < 64; i += 4) {
            a0 = fmaf(rdlane(h1, i + 0), w2c[i + 0], a0);
            a1 = fmaf(rdlane(h1, i + 1), w2c[i + 1], a1);
            a2 = fmaf(rdlane(h1, i + 2), w2c[i + 2], a2);
            a3 = fmaf(rdlane(h1, i + 3), w2c[i + 3], a3);
        }
        float h2 = fmaxf((a0 + a1) + (a2 + a3) + b2j, 0.f);
        float dv = h2 * w3j;
#pragma unroll
        for (int off = 32; off > 0; off >>= 1) dv += __shfl_xor(dv, off, 64);
        delta = dv + b3v;
        if (j == 0) out[b * NT + m] = delta;
        p0 = p1;
        p1 = pn;
    }
}

// ---------------------------------------------------------------------------
// Fallback (round-1 fused kernel) if workspace is too small for pre1.
// ---------------------------------------------------------------------------
__global__ __launch_bounds__(256) void logsig_hedge_fallback(
    const float* __restrict__ features, const float* __restrict__ W1,
    const float* __restrict__ b1, const float* __restrict__ W2,
    const float* __restrict__ b2, const float* __restrict__ W3,
    const float* __restrict__ b3, float* __restrict__ out) {
    const int b = blockIdx.x;
    const int tid = threadIdx.x;
    const int j = tid & 63;
    const int s = tid >> 6;

    __shared__ __align__(16) float sF[NT * IND];
    __shared__ __align__(16) float sSig[128];
    __shared__ float sA[IND], sB[IND], sC[IND * IND];
    __shared__ float sRel[IND];
    __shared__ __align__(16) float sPart[4 * 64];
    __shared__ __align__(16) float sH1[64];

    for (int idx = tid; idx < NT * IND; idx += 256)
        sF[idx] = features[b * (NT * IND) + idx];
    if (tid < 100) sC[tid] = 0.f;
    else if (tid < 110) sA[tid - 100] = 0.f;
    else if (tid < 120) sB[tid - 110] = 0.f;
    else if (tid >= 121 && tid < 128) sSig[tid] = 0.f;

    float vs[32], vb[32], vc[32];
#pragma unroll
    for (int mm = 0; mm < 32; ++mm) {
        int mp = 32 * s + mm;
        if (mp < 121) {
            vs[mm] = W1[(11 + mp) * 64 + j] + W1[(132 + mp) * 64 + j];
            vb[mm] = W1[(253 + mp) * 64 + j];
            vc[mm] = W1[(374 + mp) * 64 + j];
        } else { vs[mm] = 0.f; vb[mm] = 0.f; vc[mm] = 0.f; }
    }
    float ex[17];
#pragma unroll
    for (int q = 0; q < 17; ++q) ex[q] = 0.f;
    if (s == 1) {
#pragma unroll
        for (int q = 0; q < 11; ++q) ex[q] = W1[q * 64 + j];
    } else if (s == 2) {
#pragma unroll
        for (int q = 0; q < 10; ++q) ex[q] = W1[(512 + q) * 64 + j];
        ex[10] = b1[j];
    } else if (s == 3) {
#pragma unroll
        for (int q = 0; q < 17; ++q) ex[q] = W1[(495 + q) * 64 + j];
    }
    float w2p[16];
#pragma unroll
    for (int ii = 0; ii < 16; ++ii) w2p[ii] = W2[(16 * s + ii) * 64 + j];

    float w1l = 0.f, b2j = 0.f, w3j = 0.f, b3v = 0.f;
    if (s == 0) { w1l = W1[522 * 64 + j]; b2j = b2[j]; w3j = W3[j]; b3v = b3[0]; }
    float delta = 0.f;

    __syncthreads();

    for (int m = 0; m < NT; ++m) {
        if (m > 0) {
            if (tid < 100) {
                int i = tid / 10, c = tid % 10;
                float rp = sF[(m - 1) * 10 + i] - sF[i];
                float ic = sF[m * 10 + c] - sF[(m - 1) * 10 + c];
                sC[tid] += rp * ic;
            } else if (tid < 110) {
                int i = tid - 100;
                sA[i] += (float)(m - 1) * (sF[m * 10 + i] - sF[(m - 1) * 10 + i]);
            } else if (tid < 120) {
                int i = tid - 110;
                sB[i] += sF[(m - 1) * 10 + i] - sF[i];
            }
            __syncthreads();
            float inv_k = 1.0f / (float)m;
            if (tid == 0) sSig[0] = 0.5f * (float)(m - 1) * inv_k;
            else if (tid < 11) sSig[tid] = inv_k * sA[tid - 1];
            else if (tid < 121) {
                int i = tid / 11 - 1, c = tid % 11;
                sSig[tid] = (c == 0) ? inv_k * sB[i] : sC[i * 10 + (c - 1)];
            } else if (tid < 131) {
                int f = tid - 121;
                sRel[f] = sF[m * 10 + f] - sF[f];
            }
            __syncthreads();
        }
        float part = 0.f;
        if (m > 0) {
            float pa = 0.f, pb = 0.f, pc = 0.f;
#pragma unroll
            for (int q = 0; q < 8; ++q) {
                float4 sv = *(const float4*)&sSig[32 * s + 4 * q];
                pa = fmaf(sv.x, vs[4 * q + 0], pa);
                pb = fmaf(sv.x, vb[4 * q + 0], pb);
                pc = fmaf(sv.x, vc[4 * q + 0], pc);
                pa = fmaf(sv.y, vs[4 * q + 1], pa);
                pb = fmaf(sv.y, vb[4 * q + 1], pb);
                pc = fmaf(sv.y, vc[4 * q + 1], pc);
                pa = fmaf(sv.z, vs[4 * q + 2], pa);
                pb = fmaf(sv.z, vb[4 * q + 2], pb);
                pc = fmaf(sv.z, vc[4 * q + 2], pc);
                pa = fmaf(sv.w, vs[4 * q + 3], pa);
                pb = fmaf(sv.w, vb[4 * q + 3], pb);
                pc = fmaf(sv.w, vc[4 * q + 3], pc);
            }
            part = pa + sRel[0] * pb + sRel[1] * pc;
            if (s == 3) {
                float pd = 0.f;
#pragma unroll
                for (int q = 0; q < 17; ++q) pd = fmaf(sSig[q], ex[q], pd);
                part = fmaf(sRel[2], pd, part);
            }
            if (s == 1) {
                part += ex[0];
#pragma unroll
                for (int i = 0; i < 10; ++i) part = fmaf(sRel[i], ex[1 + i], part);
            }
        }
        if (s == 2) {
            float pf = ex[10];
#pragma unroll
            for (int f = 0; f < 10; ++f) pf = fmaf(sF[m * 10 + f], ex[f], pf);
            part += pf;
        }
        sPart[s * 64 + j] = part;
        __syncthreads();
        if (s == 0) {
            float x = sPart[j] + sPart[64 + j] + sPart[128 + j] + sPart[192 + j];
            sH1[j] = fmaxf(fmaf(delta, w1l, x), 0.f);
        }
        __syncthreads();
        {
            float hp = 0.f;
#pragma unroll
            for (int q = 0; q < 4; ++q) {
                float4 hv = *(const float4*)&sH1[16 * s + 4 * q];
                hp = fmaf(hv.x, w2p[4 * q + 0], hp);
                hp = fmaf(hv.y, w2p[4 * q + 1], hp);
                hp = fmaf(hv.z, w2p[4 * q + 2], hp);
                hp = fmaf(hv.w, w2p[4 * q + 3], hp);
            }
            sPart[s * 64 + j] = hp;
        }
        __syncthreads();
        if (s == 0) {
            float x2 = sPart[j] + sPart[64 + j] + sPart[128 + j] + sPart[192 + j] + b2j;
            float h2 = fmaxf(x2, 0.f);
            float dv = h2 * w3j;
#pragma unroll
            for (int off = 32; off > 0; off >>= 1) dv += __shfl_xor(dv, off, 64);
            delta = dv + b3v;
            if (j == 0) out[b * NT + m] = delta;
        }
        __syncthreads();
    }
}

extern "C" void kernel_launch(void* const* d_in, const int* in_sizes, int n_in,
                              void* d_out, int out_size, void* d_ws, size_t ws_size,
                              hipStream_t stream) {
    const float* features = (const float*)d_in[0];
    const float* W1 = (const float*)d_in[1];
    const float* b1 = (const float*)d_in[2];
    const float* W2 = (const float*)d_in[3];
    const float* b2 = (const float*)d_in[4];
    const float* W3 = (const float*)d_in[5];
    const float* b3 = (const float*)d_in[6];
    float* out = (float*)d_out;

    const size_t wr_pad   = 103936;                                 // 256B-aligned
    const size_t pre_bytes = (size_t)NB * NT * HID * sizeof(float); // 64 MiB
    if (ws_size >= wr_pad + pre_bytes) {
        float* Wr = (float*)d_ws;
        float* pre1 = (float*)((char*)d_ws + wr_pad);
        pack_kernel<<<(64 * WPJ + 255) / 256, 256, 0, stream>>>(W1, b1, Wr);
        presig_kernel<<<NB, NT, 0, stream>>>(features, Wr, pre1);
        scan_kernel<<<NB, 64, 0, stream>>>(pre1, W1, W2, b2, W3, b3, out);
    } else {
        logsig_hedge_fallback<<<NB, NT, 0, stream>>>(features, W1, b1, W2, b2, W3, b3, out);
    }
}